// Round 16
// baseline (152.329 us; speedup 1.0000x reference)
//
#include <hip/hip_runtime.h>
#include <math.h>

#define TWO_PI 6.28318530717958647692f
#define PI_F   3.14159265358979323846f
#define NORM   0.0078125f  /* 1/sqrt(128*128) */

typedef float v2f __attribute__((ext_vector_type(2)));

// ---------------------------------------------------------------- tables  [frozen]
__device__ __forceinline__ float kfreq(int i) { return (i <= 10) ? (float)i : (float)(i - 21); }

__global__ void k_tables(const float* __restrict__ thrx, const float* __restrict__ thrt,
                         float2* __restrict__ W1, float2* __restrict__ qx, float2* __restrict__ qt) {
    int t = threadIdx.x;
    if (t < 128) {
        float s, c;
        float ang = -TWO_PI * (float)t * (1.0f / 128.0f);
        sincosf(ang, &s, &c);
        W1[t] = make_float2(c, s);
    }
    for (int idx = t; idx < 21 * 128; idx += 256) {
        int i = idx >> 7, n = idx & 127;
        float k = kfreq(i), fn = (float)n;
        float s, c;
        {
            float raw = thrx[i];
            float sig = 1.0f / (1.0f + expf(-raw));
            float th = (k < 0.0f) ? (0.5f * PI_F) * (1.0f + sig) : PI_F * sig;
            float ka = fabsf(k);
            float amp = expf(-TWO_PI * ka * sinf(th) * fn * (1.0f / 128.0f));
            float a2 = TWO_PI * ka * cosf(th) * fn * (1.0f / 128.0f);
            sincosf(a2, &s, &c);
            qx[idx] = make_float2(amp * c, amp * s);
        }
        {
            float raw = thrt[i];
            float sig = 1.0f / (1.0f + expf(-raw));
            float th = (k < 0.0f) ? (0.5f * PI_F) * (1.0f + sig) : PI_F * sig;
            float ka = fabsf(k);
            float amp = expf(-TWO_PI * ka * sinf(th) * fn * (1.0f / 128.0f));
            float a2 = TWO_PI * ka * cosf(th) * fn * (1.0f / 128.0f);
            sincosf(a2, &s, &c);
            qt[idx] = make_float2(amp * c, amp * s);
        }
    }
}

// ---------------------------------------------------------------- weight transpose [co][ij] -> [ij][co]
__global__ void k_wt(const float* __restrict__ wr, const float* __restrict__ wi,
                     float2* __restrict__ Rt) {
    __shared__ float2 tile[64][65];
    const int tx = threadIdx.x & 63;
    const int ty = threadIdx.x >> 6;
    const int ij0 = blockIdx.x * 64;
    const int co0 = blockIdx.y * 64;
    #pragma unroll
    for (int r = 0; r < 16; ++r) {
        int row = ty + r * 4;
        int col = ij0 + tx;
        if (col < 441) {
            size_t g = (size_t)(co0 + row) * 441 + col;
            tile[row][tx] = make_float2(wr[g], wi[g]);
        }
    }
    __syncthreads();
    #pragma unroll
    for (int r = 0; r < 16; ++r) {
        int row = ty + r * 4;
        int ij = ij0 + row;
        if (ij < 441)
            Rt[(size_t)ij * 4096 + co0 + tx] = tile[tx][row];
    }
}

// ---------------------------------------------------------------- forward DFT (per b,c)
// Round-14 body + xs/t1s LDS UNION (xs dead before t1s written) -> 22.6 KB LDS, ~7 blocks/CU.
__launch_bounds__(256, 7)
__global__ void k_fwd(const float* __restrict__ x, const float2* __restrict__ W1,
                      float2* __restrict__ Xt) {
    __shared__ __align__(16) char ubuf[16640];       // union: xs 32*130*4 B / t1s 128*13*8 B
    __shared__ __align__(16) float2 W1s[512];        // W1 replicated 4x
    __shared__ float2 xout[231];
    float*  xs  = reinterpret_cast<float*>(ubuf);
    float2* t1s = reinterpret_cast<float2*>(ubuf);
    const int t = threadIdx.x;
    const int bid = blockIdx.x;
    const int bc = (bid & 7) * 256 + (bid >> 3);     // XCD swizzle
    const int lane = t & 63;
    const int w = t >> 6;
    const int jb = 3 * w;
    const int n0 = 2 * lane;
    const int srow = t >> 3;
    const int scol4 = (t & 7) * 4;

    const float* xg = x + (size_t)bc * 16384;

    float4 vA = *reinterpret_cast<const float4*>(xg + (srow +  0) * 128 + scol4);
    float4 vB = *reinterpret_cast<const float4*>(xg + (srow + 32) * 128 + scol4);
    float4 vC = *reinterpret_cast<const float4*>(xg + (srow + 64) * 128 + scol4);
    float4 vD = *reinterpret_cast<const float4*>(xg + (srow + 96) * 128 + scol4);

    {
        float4 v = reinterpret_cast<const float4*>(W1)[t & 63];
        reinterpret_cast<float4*>(W1s)[t] = v;
    }

    v2f arv[3], aiv[3];
    #pragma unroll
    for (int jj = 0; jj < 3; ++jj) { arv[jj] = (v2f)(0.f); aiv[jj] = (v2f)(0.f); }

    const char* W1b = reinterpret_cast<const char*>(W1s);

#define WRX(v, ro) { \
        xs[(scol4 + 0) * 130 + (ro)] = v.x; \
        xs[(scol4 + 1) * 130 + (ro)] = v.y; \
        xs[(scol4 + 2) * 130 + (ro)] = v.z; \
        xs[(scol4 + 3) * 130 + (ro)] = v.w; }

    for (int ch = 0; ch < 4; ++ch) {
        __syncthreads();
        WRX(vA, srow)      WRX(vB, srow + 32)
        WRX(vC, srow + 64) WRX(vD, srow + 96)
        __syncthreads();
        if (ch < 3) {
            const float* xn = xg + (ch + 1) * 32;
            vA = *reinterpret_cast<const float4*>(xn + (srow +  0) * 128 + scol4);
            vB = *reinterpret_cast<const float4*>(xn + (srow + 32) * 128 + scol4);
            vC = *reinterpret_cast<const float4*>(xn + (srow + 64) * 128 + scol4);
            vD = *reinterpret_cast<const float4*>(xn + (srow + 96) * 128 + scol4);
        }
        int ib0 = (((jb + 0) * ch * 32) & 127) * 8;
        int ib1 = (((jb + 1) * ch * 32) & 127) * 8;
        int ib2 = (((jb + 2) * ch * 32) & 127) * 8;
        #pragma unroll
        for (int mm = 0; mm < 32; ++mm) {
            v2f xv = *reinterpret_cast<const v2f*>(&xs[mm * 130 + n0]);
            float2 w0  = *reinterpret_cast<const float2*>(W1b + ib0);
            float2 w1v = *reinterpret_cast<const float2*>(W1b + ib1);
            float2 w2v = *reinterpret_cast<const float2*>(W1b + ib2);
            arv[0] += xv * w0.x;  aiv[0] += xv * w0.y;
            arv[1] += xv * w1v.x; aiv[1] += xv * w1v.y;
            arv[2] += xv * w2v.x; aiv[2] += xv * w2v.y;
            ib0 += (jb + 0) * 8;
            ib1 += (jb + 1) * 8;
            ib2 += (jb + 2) * 8;
        }
    }
#undef WRX
    __syncthreads();                 // xs reads done everywhere; ubuf becomes t1s
    #pragma unroll
    for (int jj = 0; jj < 3; ++jj) {
        t1s[(n0 + 0) * 13 + jb + jj] = make_float2(arv[jj].x, aiv[jj].x);
        t1s[(n0 + 1) * 13 + jb + jj] = make_float2(arv[jj].y, aiv[jj].y);
    }
    __syncthreads();
    if (t < 231) {
        int i = t / 11, j = t % 11;
        int kk = (i <= 10) ? i : i + 107;
        int ib = 0;
        v2f acc = (v2f)(0.f);
        #pragma unroll 4
        for (int nn = 0; nn < 128; ++nn) {
            float2 pv = *reinterpret_cast<const float2*>(W1b + ib);
            float2 tv = t1s[nn * 13 + j];
            v2f tp; tp.x = tv.x; tp.y = tv.y;
            v2f tn; tn.x = -tv.y; tn.y = tv.x;
            acc += tp * pv.x;
            acc += tn * pv.y;
            ib = (ib + kk * 8) & 1023;
        }
        xout[i * 11 + j] = make_float2(acc.x * NORM, acc.y * NORM);
    }
    __syncthreads();
    for (int p = t; p < 441; p += 256) {
        int i = p / 21, j = p % 21;
        float2 v;
        if (j < 11) v = xout[i * 11 + j];
        else {
            float2 u = xout[((21 - i) % 21) * 11 + (21 - j)];
            v = make_float2(u.x, -u.y);
        }
        Xt[(size_t)p * 2048 + bc] = v;
    }
}

// ---------------------------------------------------------------- channel mix (per mode)  [frozen, round-14]
__launch_bounds__(256, 2)
__global__ void k_mix(const float2* __restrict__ Xt, const float2* __restrict__ Rt,
                      float2* __restrict__ OK) {
    __shared__ float2 Xs[2048];
    __shared__ float2 Rs[4096];
    int t = threadIdx.x;
    int ij = blockIdx.x;
    {
        const float4* xrow = reinterpret_cast<const float4*>(Xt + (size_t)ij * 2048);
        for (int k = t; k < 1024; k += 256)
            reinterpret_cast<float4*>(Xs)[k] = xrow[k];
    }
    for (int k = t; k < 4096; k += 256) Rs[k] = Rt[(size_t)ij * 4096 + k];
    __syncthreads();
    int o = t & 63, bg = t >> 6;
    v2f accv[8];
    #pragma unroll
    for (int i = 0; i < 8; ++i) accv[i] = (v2f)(0.f);
    for (int c = 0; c < 64; ++c) {
        float2 rv = Rs[c * 64 + o];
        v2f rp; rp.x = rv.x;  rp.y = rv.y;
        v2f rn; rn.x = -rv.y; rn.y = rv.x;
        #pragma unroll
        for (int bb = 0; bb < 8; ++bb) {
            float2 xv = Xs[(bg * 8 + bb) * 64 + c];
            accv[bb] += rp * xv.x;
            accv[bb] += rn * xv.y;
        }
    }
    #pragma unroll
    for (int bb = 0; bb < 8; ++bb)
        OK[(size_t)ij * 2048 + (bg * 8 + bb) * 64 + o] = make_float2(accv[bb].x, accv[bb].y);
}

// ---------------------------------------------------------------- inverse DFT (per b,o)  [round-14 verbatim]
__launch_bounds__(256, 3)
__global__ void k_inv(const float2* __restrict__ OKg, const float2* __restrict__ qx,
                      const float2* __restrict__ qt, float* __restrict__ out) {
    __shared__ __align__(16) float2 qs[21 * 128];    // qx, then qt
    __shared__ __align__(16) float2 t2s[21 * 128];   // [j][n]
    __shared__ float2 oks[441];
    const int t = threadIdx.x;
    const int bo = blockIdx.x;

    for (int k = t; k < 441; k += 256) oks[k] = OKg[(size_t)k * 2048 + bo];
    for (int k = t; k < 1344; k += 256)
        reinterpret_cast<float4*>(qs)[k] = reinterpret_cast<const float4*>(qx)[k];
    __syncthreads();
    // phase A: scalar accumulators (round-6 proven)
    {
        const int ng = t & 31, jg = t >> 5;
        const int jbase = (jg < 5) ? 3 * jg : 15 + 2 * (jg - 5);
        const int jcnt  = (jg < 5) ? 3 : 2;
        float are[4][3], aim[4][3];
        #pragma unroll
        for (int r = 0; r < 4; ++r)
            #pragma unroll
            for (int jj = 0; jj < 3; ++jj) { are[r][jj] = 0.f; aim[r][jj] = 0.f; }
        for (int i = 0; i < 21; ++i) {
            float2 q0 = qs[i * 128 + ng];
            float2 q1 = qs[i * 128 + ng + 32];
            float2 q2 = qs[i * 128 + ng + 64];
            float2 q3 = qs[i * 128 + ng + 96];
            #pragma unroll
            for (int jj = 0; jj < 3; ++jj) {
                if (jj < jcnt) {
                    float2 okv = oks[i * 21 + jbase + jj];
                    are[0][jj] += okv.x * q0.x - okv.y * q0.y;
                    aim[0][jj] += okv.x * q0.y + okv.y * q0.x;
                    are[1][jj] += okv.x * q1.x - okv.y * q1.y;
                    aim[1][jj] += okv.x * q1.y + okv.y * q1.x;
                    are[2][jj] += okv.x * q2.x - okv.y * q2.y;
                    aim[2][jj] += okv.x * q2.y + okv.y * q2.x;
                    are[3][jj] += okv.x * q3.x - okv.y * q3.y;
                    aim[3][jj] += okv.x * q3.y + okv.y * q3.x;
                }
            }
        }
        #pragma unroll
        for (int jj = 0; jj < 3; ++jj) {
            if (jj < jcnt) {
                #pragma unroll
                for (int r = 0; r < 4; ++r)
                    t2s[(jbase + jj) * 128 + ng + 32 * r] = make_float2(are[r][jj], aim[r][jj]);
            }
        }
    }
    __syncthreads();
    for (int k = t; k < 1344; k += 256)
        reinterpret_cast<float4*>(qs)[k] = reinterpret_cast<const float4*>(qt)[k];
    __syncthreads();
    // phase B: wave w owns rows w*32 + nh*16 + r (r<16); lane owns m = ml + 32q
    {
        const int lane = t & 63, w = t >> 6;
        const int ml = lane & 31;
        const int nh = lane >> 5;
        const int nbase = w * 32 + nh * 16;

#define DECLR(r) v2f a01_##r = (v2f)(0.f); v2f a23_##r = (v2f)(0.f);
        DECLR(0)  DECLR(1)  DECLR(2)  DECLR(3)
        DECLR(4)  DECLR(5)  DECLR(6)  DECLR(7)
        DECLR(8)  DECLR(9)  DECLR(10) DECLR(11)
        DECLR(12) DECLR(13) DECLR(14) DECLR(15)

#define UPDR(r) { float2 tv = trow[r]; \
            a01_##r += qx01 * tv.x; a01_##r += qyn01 * tv.y; \
            a23_##r += qx23 * tv.x; a23_##r += qyn23 * tv.y; }

        for (int j = 0; j < 21; ++j) {
            float2 q0 = qs[j * 128 + ml];
            float2 q1 = qs[j * 128 + ml + 32];
            float2 q2 = qs[j * 128 + ml + 64];
            float2 q3 = qs[j * 128 + ml + 96];
            v2f qx01, qyn01, qx23, qyn23;
            qx01.x = q0.x;   qx01.y = q1.x;
            qyn01.x = -q0.y; qyn01.y = -q1.y;
            qx23.x = q2.x;   qx23.y = q3.x;
            qyn23.x = -q2.y; qyn23.y = -q3.y;
            const float2* trow = t2s + j * 128 + nbase;
            UPDR(0)  UPDR(1)  UPDR(2)  UPDR(3)
            UPDR(4)  UPDR(5)  UPDR(6)  UPDR(7)
            UPDR(8)  UPDR(9)  UPDR(10) UPDR(11)
            UPDR(12) UPDR(13) UPDR(14) UPDR(15)
        }
        float* og = out + (size_t)bo * 16384;
#define STOR(r) og[(nbase + r) * 128 + ml      ] = a01_##r.x * NORM; \
                og[(nbase + r) * 128 + ml + 32 ] = a01_##r.y * NORM; \
                og[(nbase + r) * 128 + ml + 64 ] = a23_##r.x * NORM; \
                og[(nbase + r) * 128 + ml + 96 ] = a23_##r.y * NORM;
        STOR(0)  STOR(1)  STOR(2)  STOR(3)
        STOR(4)  STOR(5)  STOR(6)  STOR(7)
        STOR(8)  STOR(9)  STOR(10) STOR(11)
        STOR(12) STOR(13) STOR(14) STOR(15)
#undef DECLR
#undef UPDR
#undef STOR
    }
}

// ---------------------------------------------------------------- launch
extern "C" void kernel_launch(void* const* d_in, const int* in_sizes, int n_in,
                              void* d_out, int out_size, void* d_ws, size_t ws_size,
                              hipStream_t stream) {
    const float* x   = (const float*)d_in[0];
    const float* wr  = (const float*)d_in[1];
    const float* wi  = (const float*)d_in[2];
    const float* thx = (const float*)d_in[3];
    const float* tht = (const float*)d_in[4];
    float* out = (float*)d_out;

    char* ws = (char*)d_ws;
    float2* W1 = (float2*)(ws);                                   // 1024 B (slot 21504)
    float2* qx = (float2*)(ws + 21504);
    float2* qt = (float2*)(ws + 43008);
    float2* Rt = (float2*)(ws + 64512);                           // 14450688 B
    float2* Xt = (float2*)(ws + 64512 + 14450688);                // [448][2048] f2 = 7340032 B
    float2* OK = (float2*)(ws + 64512 + 14450688 + 7340032);      // 7225344 B

    k_tables<<<1, 256, 0, stream>>>(thx, tht, W1, qx, qt);
    k_wt<<<dim3(7, 64), 256, 0, stream>>>(wr, wi, Rt);
    k_fwd<<<2048, 256, 0, stream>>>(x, W1, Xt);
    k_mix<<<441, 256, 0, stream>>>(Xt, Rt, OK);
    k_inv<<<2048, 256, 0, stream>>>(OK, qx, qt, out);
}

// Round 17
// 134.259 us; speedup vs baseline: 1.1346x; 1.1346x over previous
//
#include <hip/hip_runtime.h>
#include <math.h>

#define TWO_PI 6.28318530717958647692f
#define PI_F   3.14159265358979323846f
#define NORM   0.0078125f  /* 1/sqrt(128*128) */

typedef float v2f  __attribute__((ext_vector_type(2)));
typedef short sh8  __attribute__((ext_vector_type(8)));
typedef float f32x4 __attribute__((ext_vector_type(4)));

__device__ __forceinline__ unsigned short f2bf(float f) {
    unsigned int u = __float_as_uint(f);
    unsigned int r = (u + 0x7FFFu + ((u >> 16) & 1u)) >> 16;   // RNE
    return (unsigned short)r;
}

// ---------------------------------------------------------------- tables
// W1 fp32, qx fp32 (phase A), qt -> bf16 TRANSPOSED tables qtbr/qtbi[m][k32] (phase B MFMA)
__device__ __forceinline__ float kfreq(int i) { return (i <= 10) ? (float)i : (float)(i - 21); }

__global__ void k_tables(const float* __restrict__ thrx, const float* __restrict__ thrt,
                         float2* __restrict__ W1, float2* __restrict__ qx,
                         unsigned short* __restrict__ qtbr, unsigned short* __restrict__ qtbi) {
    int t = threadIdx.x;
    if (t < 128) {
        float s, c;
        float ang = -TWO_PI * (float)t * (1.0f / 128.0f);
        sincosf(ang, &s, &c);
        W1[t] = make_float2(c, s);
    }
    for (int idx = t; idx < 21 * 128; idx += 256) {
        int i = idx >> 7, n = idx & 127;
        float k = kfreq(i), fn = (float)n;
        float s, c;
        {
            float raw = thrx[i];
            float sig = 1.0f / (1.0f + expf(-raw));
            float th = (k < 0.0f) ? (0.5f * PI_F) * (1.0f + sig) : PI_F * sig;
            float ka = fabsf(k);
            float amp = expf(-TWO_PI * ka * sinf(th) * fn * (1.0f / 128.0f));
            float a2 = TWO_PI * ka * cosf(th) * fn * (1.0f / 128.0f);
            sincosf(a2, &s, &c);
            qx[idx] = make_float2(amp * c, amp * s);
        }
        {
            float raw = thrt[i];
            float sig = 1.0f / (1.0f + expf(-raw));
            float th = (k < 0.0f) ? (0.5f * PI_F) * (1.0f + sig) : PI_F * sig;
            float ka = fabsf(k);
            float amp = expf(-TWO_PI * ka * sinf(th) * fn * (1.0f / 128.0f));
            float a2 = TWO_PI * ka * cosf(th) * fn * (1.0f / 128.0f);
            sincosf(a2, &s, &c);
            qtbr[n * 32 + i] = f2bf(amp * c);
            qtbi[n * 32 + i] = f2bf(amp * s);
        }
    }
    for (int z = t; z < 128 * 11; z += 256) {     // zero-pad k = 21..31
        int n = z / 11, kz = 21 + z % 11;
        qtbr[n * 32 + kz] = 0;
        qtbi[n * 32 + kz] = 0;
    }
}

// ---------------------------------------------------------------- weight transpose [co][ij] -> [ij][co]
__global__ void k_wt(const float* __restrict__ wr, const float* __restrict__ wi,
                     float2* __restrict__ Rt) {
    __shared__ float2 tile[64][65];
    const int tx = threadIdx.x & 63;
    const int ty = threadIdx.x >> 6;
    const int ij0 = blockIdx.x * 64;
    const int co0 = blockIdx.y * 64;
    #pragma unroll
    for (int r = 0; r < 16; ++r) {
        int row = ty + r * 4;
        int col = ij0 + tx;
        if (col < 441) {
            size_t g = (size_t)(co0 + row) * 441 + col;
            tile[row][tx] = make_float2(wr[g], wi[g]);
        }
    }
    __syncthreads();
    #pragma unroll
    for (int r = 0; r < 16; ++r) {
        int row = ty + r * 4;
        int ij = ij0 + row;
        if (ij < 441)
            Rt[(size_t)ij * 4096 + co0 + tx] = tile[tx][row];
    }
}

// ---------------------------------------------------------------- forward DFT (per b,c)  [frozen, round-16]
__launch_bounds__(256, 7)
__global__ void k_fwd(const float* __restrict__ x, const float2* __restrict__ W1,
                      float2* __restrict__ Xt) {
    __shared__ __align__(16) char ubuf[16640];
    __shared__ __align__(16) float2 W1s[512];
    __shared__ float2 xout[231];
    float*  xs  = reinterpret_cast<float*>(ubuf);
    float2* t1s = reinterpret_cast<float2*>(ubuf);
    const int t = threadIdx.x;
    const int bid = blockIdx.x;
    const int bc = (bid & 7) * 256 + (bid >> 3);
    const int lane = t & 63;
    const int w = t >> 6;
    const int jb = 3 * w;
    const int n0 = 2 * lane;
    const int srow = t >> 3;
    const int scol4 = (t & 7) * 4;

    const float* xg = x + (size_t)bc * 16384;

    float4 vA = *reinterpret_cast<const float4*>(xg + (srow +  0) * 128 + scol4);
    float4 vB = *reinterpret_cast<const float4*>(xg + (srow + 32) * 128 + scol4);
    float4 vC = *reinterpret_cast<const float4*>(xg + (srow + 64) * 128 + scol4);
    float4 vD = *reinterpret_cast<const float4*>(xg + (srow + 96) * 128 + scol4);

    {
        float4 v = reinterpret_cast<const float4*>(W1)[t & 63];
        reinterpret_cast<float4*>(W1s)[t] = v;
    }

    v2f arv[3], aiv[3];
    #pragma unroll
    for (int jj = 0; jj < 3; ++jj) { arv[jj] = (v2f)(0.f); aiv[jj] = (v2f)(0.f); }

    const char* W1b = reinterpret_cast<const char*>(W1s);

#define WRX(v, ro) { \
        xs[(scol4 + 0) * 130 + (ro)] = v.x; \
        xs[(scol4 + 1) * 130 + (ro)] = v.y; \
        xs[(scol4 + 2) * 130 + (ro)] = v.z; \
        xs[(scol4 + 3) * 130 + (ro)] = v.w; }

    for (int ch = 0; ch < 4; ++ch) {
        __syncthreads();
        WRX(vA, srow)      WRX(vB, srow + 32)
        WRX(vC, srow + 64) WRX(vD, srow + 96)
        __syncthreads();
        if (ch < 3) {
            const float* xn = xg + (ch + 1) * 32;
            vA = *reinterpret_cast<const float4*>(xn + (srow +  0) * 128 + scol4);
            vB = *reinterpret_cast<const float4*>(xn + (srow + 32) * 128 + scol4);
            vC = *reinterpret_cast<const float4*>(xn + (srow + 64) * 128 + scol4);
            vD = *reinterpret_cast<const float4*>(xn + (srow + 96) * 128 + scol4);
        }
        int ib0 = (((jb + 0) * ch * 32) & 127) * 8;
        int ib1 = (((jb + 1) * ch * 32) & 127) * 8;
        int ib2 = (((jb + 2) * ch * 32) & 127) * 8;
        #pragma unroll
        for (int mm = 0; mm < 32; ++mm) {
            v2f xv = *reinterpret_cast<const v2f*>(&xs[mm * 130 + n0]);
            float2 w0  = *reinterpret_cast<const float2*>(W1b + ib0);
            float2 w1v = *reinterpret_cast<const float2*>(W1b + ib1);
            float2 w2v = *reinterpret_cast<const float2*>(W1b + ib2);
            arv[0] += xv * w0.x;  aiv[0] += xv * w0.y;
            arv[1] += xv * w1v.x; aiv[1] += xv * w1v.y;
            arv[2] += xv * w2v.x; aiv[2] += xv * w2v.y;
            ib0 += (jb + 0) * 8;
            ib1 += (jb + 1) * 8;
            ib2 += (jb + 2) * 8;
        }
    }
#undef WRX
    __syncthreads();
    #pragma unroll
    for (int jj = 0; jj < 3; ++jj) {
        t1s[(n0 + 0) * 13 + jb + jj] = make_float2(arv[jj].x, aiv[jj].x);
        t1s[(n0 + 1) * 13 + jb + jj] = make_float2(arv[jj].y, aiv[jj].y);
    }
    __syncthreads();
    if (t < 231) {
        int i = t / 11, j = t % 11;
        int kk = (i <= 10) ? i : i + 107;
        int ib = 0;
        v2f acc = (v2f)(0.f);
        #pragma unroll 4
        for (int nn = 0; nn < 128; ++nn) {
            float2 pv = *reinterpret_cast<const float2*>(W1b + ib);
            float2 tv = t1s[nn * 13 + j];
            v2f tp; tp.x = tv.x; tp.y = tv.y;
            v2f tn; tn.x = -tv.y; tn.y = tv.x;
            acc += tp * pv.x;
            acc += tn * pv.y;
            ib = (ib + kk * 8) & 1023;
        }
        xout[i * 11 + j] = make_float2(acc.x * NORM, acc.y * NORM);
    }
    __syncthreads();
    for (int p = t; p < 441; p += 256) {
        int i = p / 21, j = p % 21;
        float2 v;
        if (j < 11) v = xout[i * 11 + j];
        else {
            float2 u = xout[((21 - i) % 21) * 11 + (21 - j)];
            v = make_float2(u.x, -u.y);
        }
        Xt[(size_t)p * 2048 + bc] = v;
    }
}

// ---------------------------------------------------------------- channel mix (per mode)  [frozen, round-14]
__launch_bounds__(256, 2)
__global__ void k_mix(const float2* __restrict__ Xt, const float2* __restrict__ Rt,
                      float2* __restrict__ OK) {
    __shared__ float2 Xs[2048];
    __shared__ float2 Rs[4096];
    int t = threadIdx.x;
    int ij = blockIdx.x;
    {
        const float4* xrow = reinterpret_cast<const float4*>(Xt + (size_t)ij * 2048);
        for (int k = t; k < 1024; k += 256)
            reinterpret_cast<float4*>(Xs)[k] = xrow[k];
    }
    for (int k = t; k < 4096; k += 256) Rs[k] = Rt[(size_t)ij * 4096 + k];
    __syncthreads();
    int o = t & 63, bg = t >> 6;
    v2f accv[8];
    #pragma unroll
    for (int i = 0; i < 8; ++i) accv[i] = (v2f)(0.f);
    for (int c = 0; c < 64; ++c) {
        float2 rv = Rs[c * 64 + o];
        v2f rp; rp.x = rv.x;  rp.y = rv.y;
        v2f rn; rn.x = -rv.y; rn.y = rv.x;
        #pragma unroll
        for (int bb = 0; bb < 8; ++bb) {
            float2 xv = Xs[(bg * 8 + bb) * 64 + c];
            accv[bb] += rp * xv.x;
            accv[bb] += rn * xv.y;
        }
    }
    #pragma unroll
    for (int bb = 0; bb < 8; ++bb)
        OK[(size_t)ij * 2048 + (bg * 8 + bb) * 64 + o] = make_float2(accv[bb].x, accv[bb].y);
}

// ---------------------------------------------------------------- inverse DFT (per b,o)
// phase A: scalar (round-6 proven), t2s[j][n] fp32.
// phase B: MFMA 16x16x32 bf16: out = T2r^T @ qtr - T2i^T @ qti  (K=21 pad 32).
__launch_bounds__(256, 3)
__global__ void k_inv(const float2* __restrict__ OKg, const float2* __restrict__ qx,
                      const unsigned short* __restrict__ qtbg, float* __restrict__ out) {
    __shared__ __align__(16) float2 qs[21 * 128];    // phase A: qx fp32; phase B: qtb bf16 (16KB)
    __shared__ __align__(16) float2 t2s[21 * 128];   // [j][n]
    __shared__ float2 oks[441];
    const int t = threadIdx.x;
    const int bo = blockIdx.x;

    for (int k = t; k < 441; k += 256) oks[k] = OKg[(size_t)k * 2048 + bo];
    for (int k = t; k < 1344; k += 256)
        reinterpret_cast<float4*>(qs)[k] = reinterpret_cast<const float4*>(qx)[k];
    __syncthreads();
    // phase A: scalar accumulators (proven)
    {
        const int ng = t & 31, jg = t >> 5;
        const int jbase = (jg < 5) ? 3 * jg : 15 + 2 * (jg - 5);
        const int jcnt  = (jg < 5) ? 3 : 2;
        float are[4][3], aim[4][3];
        #pragma unroll
        for (int r = 0; r < 4; ++r)
            #pragma unroll
            for (int jj = 0; jj < 3; ++jj) { are[r][jj] = 0.f; aim[r][jj] = 0.f; }
        for (int i = 0; i < 21; ++i) {
            float2 q0 = qs[i * 128 + ng];
            float2 q1 = qs[i * 128 + ng + 32];
            float2 q2 = qs[i * 128 + ng + 64];
            float2 q3 = qs[i * 128 + ng + 96];
            #pragma unroll
            for (int jj = 0; jj < 3; ++jj) {
                if (jj < jcnt) {
                    float2 okv = oks[i * 21 + jbase + jj];
                    are[0][jj] += okv.x * q0.x - okv.y * q0.y;
                    aim[0][jj] += okv.x * q0.y + okv.y * q0.x;
                    are[1][jj] += okv.x * q1.x - okv.y * q1.y;
                    aim[1][jj] += okv.x * q1.y + okv.y * q1.x;
                    are[2][jj] += okv.x * q2.x - okv.y * q2.y;
                    aim[2][jj] += okv.x * q2.y + okv.y * q2.x;
                    are[3][jj] += okv.x * q3.x - okv.y * q3.y;
                    aim[3][jj] += okv.x * q3.y + okv.y * q3.x;
                }
            }
        }
        #pragma unroll
        for (int jj = 0; jj < 3; ++jj) {
            if (jj < jcnt) {
                #pragma unroll
                for (int r = 0; r < 4; ++r)
                    t2s[(jbase + jj) * 128 + ng + 32 * r] = make_float2(are[r][jj], aim[r][jj]);
            }
        }
    }
    __syncthreads();
    {   // stage bf16 qt tables (16 KB) into qs
        float4* dst = reinterpret_cast<float4*>(qs);
        const float4* src = reinterpret_cast<const float4*>(qtbg);
        for (int k = t; k < 1024; k += 256) dst[k] = src[k];
    }
    __syncthreads();
    // phase B: MFMA. wave w -> rows 32w..32w+31 (2 tile-rows); 8 tile-cols.
    {
        const int lane = t & 63, w = t >> 6;
        const int q = lane >> 4, c16 = lane & 15;
        const unsigned short* qtbr_l = reinterpret_cast<const unsigned short*>(qs);
        const unsigned short* qtbi_l = qtbr_l + 4096;

        sh8 ar0 = (sh8)0, ai0 = (sh8)0, ar1 = (sh8)0, ai1 = (sh8)0;
        #pragma unroll
        for (int i = 0; i < 8; ++i) {
            int k = 8 * q + i;
            int kc = (k <= 20) ? k : 20;
            bool val = (k <= 20);
            float2 v0 = t2s[kc * 128 + 32 * w + c16];
            float2 v1 = t2s[kc * 128 + 32 * w + 16 + c16];
            ar0[i] = val ? (short)f2bf(v0.x)  : (short)0;
            ai0[i] = val ? (short)f2bf(-v0.y) : (short)0;
            ar1[i] = val ? (short)f2bf(v1.x)  : (short)0;
            ai1[i] = val ? (short)f2bf(-v1.y) : (short)0;
        }
        float* og = out + (size_t)bo * 16384;
        #pragma unroll
        for (int mc = 0; mc < 8; ++mc) {
            sh8 br = *reinterpret_cast<const sh8*>(qtbr_l + (16 * mc + c16) * 32 + 8 * q);
            sh8 bi = *reinterpret_cast<const sh8*>(qtbi_l + (16 * mc + c16) * 32 + 8 * q);
            f32x4 acc0 = (f32x4)(0.f);
            acc0 = __builtin_amdgcn_mfma_f32_16x16x32_bf16(ar0, br, acc0, 0, 0, 0);
            acc0 = __builtin_amdgcn_mfma_f32_16x16x32_bf16(ai0, bi, acc0, 0, 0, 0);
            f32x4 acc1 = (f32x4)(0.f);
            acc1 = __builtin_amdgcn_mfma_f32_16x16x32_bf16(ar1, br, acc1, 0, 0, 0);
            acc1 = __builtin_amdgcn_mfma_f32_16x16x32_bf16(ai1, bi, acc1, 0, 0, 0);
            #pragma unroll
            for (int reg = 0; reg < 4; ++reg) {
                og[(32 * w + 4 * q + reg) * 128 + 16 * mc + c16]      = acc0[reg] * NORM;
                og[(32 * w + 16 + 4 * q + reg) * 128 + 16 * mc + c16] = acc1[reg] * NORM;
            }
        }
    }
}

// ---------------------------------------------------------------- launch
extern "C" void kernel_launch(void* const* d_in, const int* in_sizes, int n_in,
                              void* d_out, int out_size, void* d_ws, size_t ws_size,
                              hipStream_t stream) {
    const float* x   = (const float*)d_in[0];
    const float* wr  = (const float*)d_in[1];
    const float* wi  = (const float*)d_in[2];
    const float* thx = (const float*)d_in[3];
    const float* tht = (const float*)d_in[4];
    float* out = (float*)d_out;

    char* ws = (char*)d_ws;
    float2* W1 = (float2*)(ws);                                   // 1024 B (slot 21504)
    float2* qx = (float2*)(ws + 21504);                           // 21504 B
    unsigned short* qtbr = (unsigned short*)(ws + 43008);         // [128][32] bf16, 8192 B
    unsigned short* qtbi = (unsigned short*)(ws + 43008 + 8192);  // [128][32] bf16, 8192 B
    float2* Rt = (float2*)(ws + 64512);                           // 14450688 B
    float2* Xt = (float2*)(ws + 64512 + 14450688);                // [448][2048] f2 = 7340032 B
    float2* OK = (float2*)(ws + 64512 + 14450688 + 7340032);      // 7225344 B

    k_tables<<<1, 256, 0, stream>>>(thx, tht, W1, qx, qtbr, qtbi);
    k_wt<<<dim3(7, 64), 256, 0, stream>>>(wr, wi, Rt);
    k_fwd<<<2048, 256, 0, stream>>>(x, W1, Xt);
    k_mix<<<441, 256, 0, stream>>>(Xt, Rt, OK);
    k_inv<<<2048, 256, 0, stream>>>(OK, qx, (const unsigned short*)(ws + 43008), out);
}